// Round 1
// baseline (149.070 us; speedup 1.0000x reference)
//
#include <hip/hip_runtime.h>
#include <hip/hip_bf16.h>

// AttentionHead: out = softmax((q@Wq^T+bq) @ (k@Wk^T+bk)^T / 16) @ (v@Wv^T+bv)
// N=8192, DK=DV=256. f32 in/out, bf16 MFMA internally.
//
// ws layout (total ~44.3 MB):
//   [0,4M)    Qs  bf16 [8192][256]  (pre-scaled by 1/16)
//   [4M,8M)   Ks  bf16 [8192][256]
//   [8M,12M)  Vt  bf16 [256][8192]  (V transposed)
//   [12M,44M) Op  f32  [4][8192][256] (per-split unnormalized O)
//   [44M,+256K) Ml float2 [4][8192]  (per-split m,l)

typedef __attribute__((ext_vector_type(8))) short short8;
typedef __attribute__((ext_vector_type(4))) short short4v;
typedef __attribute__((ext_vector_type(4))) float f32x4;
typedef __attribute__((ext_vector_type(4))) float float4v;

#define MFMA16 __builtin_amdgcn_mfma_f32_16x16x32_bf16

namespace {
constexpr int kN  = 8192;
constexpr int kD  = 256;   // DK == DV == 256
constexpr int kQB = 128;   // q rows per flash block (4 waves x 32)
constexpr int kKVB = 64;   // kv rows per iteration
constexpr int kSplit = 4;  // kv splits (merged afterwards)
constexpr int kKVRange = kN / kSplit;  // 2048
}

__device__ __forceinline__ unsigned short f2bf(float x) {
  union { float f; unsigned u; } v; v.f = x;
  unsigned r = v.u + 0x7FFFu + ((v.u >> 16) & 1u);  // RNE
  return (unsigned short)(r >> 16);
}

// ---------------------------------------------------------------------------
// proj: Y = X @ W^T + b, bf16 out.  mode 0: Qs (x 1/16); 1: Ks; 2: Vt (transposed)
// grid (128, 4, 3), block 256. Tile 64x64, K=256 staged whole in LDS.
// ---------------------------------------------------------------------------
__global__ __launch_bounds__(256) void proj_kernel(
    const float* __restrict__ qx, const float* __restrict__ kx, const float* __restrict__ vx,
    const float* __restrict__ Wq, const float* __restrict__ bq,
    const float* __restrict__ Wk, const float* __restrict__ bk,
    const float* __restrict__ Wv, const float* __restrict__ bv,
    short* __restrict__ Qs, short* __restrict__ Ks, short* __restrict__ Vt)
{
  const int mode = blockIdx.z;
  const float* X; const float* W; const float* B;
  if (mode == 0)      { X = qx; W = Wq; B = bq; }
  else if (mode == 1) { X = kx; W = Wk; B = bk; }
  else                { X = vx; W = Wv; B = bv; }

  const int nb = blockIdx.x * 64;
  const int ob = blockIdx.y * 64;

  __shared__ short XA[64][264];  // +8 pad: 528B row stride, 2-way banks on b128 reads
  __shared__ short WB[64][264];

  const int t  = threadIdx.x;
  {
    const int c4 = t & 63;       // float4 column
    const int r0 = t >> 6;       // 4 rows/pass
#pragma unroll
    for (int p = 0; p < 16; ++p) {
      const int r = p * 4 + r0;
      float4v xv = *(const float4v*)(X + (size_t)(nb + r) * kD + c4 * 4);
      float4v wv = *(const float4v*)(W + (size_t)(ob + r) * kD + c4 * 4);
      short4v xs, wsv;
#pragma unroll
      for (int j = 0; j < 4; ++j) { xs[j] = (short)f2bf(xv[j]); wsv[j] = (short)f2bf(wv[j]); }
      *(short4v*)(&XA[r][c4 * 4]) = xs;
      *(short4v*)(&WB[r][c4 * 4]) = wsv;
    }
  }
  __syncthreads();

  const int w  = t >> 6;
  const int l  = t & 63;
  const int lr = l & 15;
  const int g  = l >> 4;

  const f32x4 vzero = {0.f, 0.f, 0.f, 0.f};
  f32x4 acc[4];
#pragma unroll
  for (int ct = 0; ct < 4; ++ct) acc[ct] = vzero;

#pragma unroll
  for (int s = 0; s < 8; ++s) {
    short8 af = *(const short8*)(&XA[w * 16 + lr][s * 32 + g * 8]);
#pragma unroll
    for (int ct = 0; ct < 4; ++ct) {
      short8 bf = *(const short8*)(&WB[ct * 16 + lr][s * 32 + g * 8]);
      acc[ct] = MFMA16(af, bf, acc[ct], 0, 0, 0);
    }
  }

  // D layout: col = lane&15 (o), row = 4*(lane>>4)+reg (n)
#pragma unroll
  for (int ct = 0; ct < 4; ++ct) {
    const int o = ob + ct * 16 + lr;
    const float bias = B[o];
    if (mode == 2) {
      const int n0 = nb + w * 16 + g * 4;
      short4v vs;
#pragma unroll
      for (int r2 = 0; r2 < 4; ++r2) vs[r2] = (short)f2bf(acc[ct][r2] + bias);
      *(short4v*)(Vt + (size_t)o * kN + n0) = vs;   // 4 contiguous n: 8B store
    } else {
      short* Out = (mode == 0) ? Qs : Ks;
      const float sc = (mode == 0) ? 0.0625f : 1.0f;
#pragma unroll
      for (int r2 = 0; r2 < 4; ++r2) {
        const int n = nb + w * 16 + g * 4 + r2;
        Out[(size_t)n * kD + o] = (short)f2bf((acc[ct][r2] + bias) * sc);
      }
    }
  }
}

// ---------------------------------------------------------------------------
// flash: per block: 128 q rows (4 waves x 32), one kv split (2048 rows),
// KVB=64 per iteration. Swapped QK^T (S^T = K@Q^T) so the kv-reduction is
// 2 shfl_xor; P goes through per-wave LDS to become the PV A-operand.
// grid (64, 4) -> 256 blocks (1/CU); XCD remap gives each XCD one split.
// ---------------------------------------------------------------------------
__global__ __launch_bounds__(256, 1) void flash_kernel(
    const short* __restrict__ Qs, const short* __restrict__ Ks, const short* __restrict__ Vt,
    float* __restrict__ Op, float2* __restrict__ Ml)
{
  // bijective remap of 256 blocks: xcd = hwid&7 -> sp = xcd>>1 (2 XCDs/split)
  const int linear = (int)blockIdx.x + ((int)blockIdx.y << 6);
  const int xcd = linear & 7;
  const int idx = linear >> 3;           // 0..31
  const int sp  = xcd >> 1;              // 0..3
  const int qt  = ((xcd & 1) << 5) + idx; // 0..63
  const int kv_base = sp * kKVRange;

  __shared__ short KL[64][264];          // K tile  [kv][dk], pad 8
  __shared__ short VL[256][72];          // Vt tile [dv][kv], pad 8
  __shared__ short PL[4][2][16][72];     // per-wave P [qs][q][kv], pad 8

  const int t = threadIdx.x;
  const int w = t >> 6, l = t & 63, lr = l & 15, g = l >> 4;

  // Q fragments in registers: 32 rows x 256 dk per wave (64 VGPR)
  short8 qf[2][8];
#pragma unroll
  for (int qs = 0; qs < 2; ++qs) {
    const size_t qrow = (size_t)qt * kQB + w * 32 + qs * 16 + lr;
#pragma unroll
    for (int s = 0; s < 8; ++s)
      qf[qs][s] = *(const short8*)(Qs + qrow * kD + s * 32 + g * 8);
  }

  const f32x4 vzero = {0.f, 0.f, 0.f, 0.f};
  f32x4 oacc[2][16];
#pragma unroll
  for (int qs = 0; qs < 2; ++qs)
#pragma unroll
    for (int dvt = 0; dvt < 16; ++dvt) oacc[qs][dvt] = vzero;
  float m_reg[2] = {-1e30f, -1e30f};
  float l_reg[2] = {0.f, 0.f};

  const int cK = t & 31, rK = t >> 5;   // K stage: 32 thr/row
  const int cV = t & 7,  rV = t >> 3;   // V stage: 8 thr/row

  for (int it = 0; it < kKVRange / kKVB; ++it) {
    const int kv0 = kv_base + it * kKVB;
    __syncthreads();  // protect LDS reuse from previous iteration
#pragma unroll
    for (int p = 0; p < 8; ++p) {
      const int r = p * 8 + rK;
      *(short8*)(&KL[r][cK * 8]) = *(const short8*)(Ks + (size_t)(kv0 + r) * kD + cK * 8);
    }
#pragma unroll
    for (int p = 0; p < 8; ++p) {
      const int dv = p * 32 + rV;
      *(short8*)(&VL[dv][cV * 8]) = *(const short8*)(Vt + (size_t)dv * kN + kv0 + cV * 8);
    }
    __syncthreads();

    // ---- QK^T: S^T[kv][q], 4 kv-tiles x 2 q-subtiles, K frag reused x2 ----
    f32x4 sacc[4][2];
#pragma unroll
    for (int tt = 0; tt < 4; ++tt) { sacc[tt][0] = vzero; sacc[tt][1] = vzero; }
#pragma unroll
    for (int tt = 0; tt < 4; ++tt) {
#pragma unroll
      for (int s = 0; s < 8; ++s) {
        short8 kf = *(const short8*)(&KL[tt * 16 + lr][s * 32 + g * 8]);
        sacc[tt][0] = MFMA16(kf, qf[0][s], sacc[tt][0], 0, 0, 0);
        sacc[tt][1] = MFMA16(kf, qf[1][s], sacc[tt][1], 0, 0, 0);
      }
    }

    // ---- online softmax per q column (q = lr). lane's S^T rows: kv=16t+4g+r
    float corrv[2];
#pragma unroll
    for (int qs = 0; qs < 2; ++qs) {
      float pmax = -1e30f;
#pragma unroll
      for (int tt = 0; tt < 4; ++tt)
#pragma unroll
        for (int r2 = 0; r2 < 4; ++r2) pmax = fmaxf(pmax, sacc[tt][qs][r2]);
      pmax = fmaxf(pmax, __shfl_xor(pmax, 16));
      pmax = fmaxf(pmax, __shfl_xor(pmax, 32));
      const float newm = fmaxf(m_reg[qs], pmax);
      const float corr = __expf(m_reg[qs] - newm);  // first iter: exp(-1e30-x)=0
      float psum = 0.f;
#pragma unroll
      for (int tt = 0; tt < 4; ++tt) {
        short4v ps;
#pragma unroll
        for (int r2 = 0; r2 < 4; ++r2) {
          const float p = __expf(sacc[tt][qs][r2] - newm);
          psum += p;
          ps[r2] = (short)f2bf(p);
        }
        *(short4v*)(&PL[w][qs][lr][tt * 16 + g * 4]) = ps;  // P[q=lr][kv]
      }
      psum += __shfl_xor(psum, 16);
      psum += __shfl_xor(psum, 32);
      l_reg[qs] = l_reg[qs] * corr + psum;
      m_reg[qs] = newm;
      corrv[qs] = corr;
    }
    __syncthreads();  // PL write -> read (also guarantees lgkmcnt drain)

    // ---- O rescale: O rows are q=4g+r; fetch corr for those q via shfl ----
#pragma unroll
    for (int qs = 0; qs < 2; ++qs) {
      f32x4 cs;
#pragma unroll
      for (int r2 = 0; r2 < 4; ++r2) cs[r2] = __shfl(corrv[qs], g * 4 + r2);
#pragma unroll
      for (int dvt = 0; dvt < 16; ++dvt) oacc[qs][dvt] *= cs;
    }

    // ---- PV: O[q][dv] += P @ V.  A=P from PL, B=V from VL (both contiguous)
    short8 pa[2][2];
#pragma unroll
    for (int qs = 0; qs < 2; ++qs)
#pragma unroll
      for (int ks = 0; ks < 2; ++ks)
        pa[qs][ks] = *(const short8*)(&PL[w][qs][lr][ks * 32 + g * 8]);
#pragma unroll
    for (int dvt = 0; dvt < 16; ++dvt) {
#pragma unroll
      for (int ks = 0; ks < 2; ++ks) {
        short8 vb = *(const short8*)(&VL[dvt * 16 + lr][ks * 32 + g * 8]);
        oacc[0][dvt] = MFMA16(pa[0][ks], vb, oacc[0][dvt], 0, 0, 0);
        oacc[1][dvt] = MFMA16(pa[1][ks], vb, oacc[1][dvt], 0, 0, 0);
      }
    }
  }

  // ---- per-split partials ----
#pragma unroll
  for (int qs = 0; qs < 2; ++qs)
#pragma unroll
    for (int dvt = 0; dvt < 16; ++dvt)
#pragma unroll
      for (int r2 = 0; r2 < 4; ++r2) {
        const size_t qrow = (size_t)qt * kQB + w * 32 + qs * 16 + g * 4 + r2;
        Op[((size_t)sp * kN + qrow) * kD + dvt * 16 + lr] = oacc[qs][dvt][r2];
      }
  if (g == 0) {
#pragma unroll
    for (int qs = 0; qs < 2; ++qs) {
      const size_t qrow = (size_t)qt * kQB + w * 32 + qs * 16 + lr;
      Ml[(size_t)sp * kN + qrow] = make_float2(m_reg[qs], l_reg[qs]);
    }
  }
}

// ---------------------------------------------------------------------------
// merge: combine kSplit partials per q row and normalize. grid 8192, block 256.
// ---------------------------------------------------------------------------
__global__ __launch_bounds__(256) void merge_kernel(
    const float* __restrict__ Op, const float2* __restrict__ Ml, float* __restrict__ out)
{
  const int qrow = blockIdx.x;
  const int d = threadIdx.x;
  float m[kSplit], li[kSplit];
  float M = -1e30f;
#pragma unroll
  for (int s = 0; s < kSplit; ++s) {
    const float2 a = Ml[(size_t)s * kN + qrow];
    m[s] = a.x; li[s] = a.y;
    M = fmaxf(M, m[s]);
  }
  float L = 0.f, accv = 0.f;
#pragma unroll
  for (int s = 0; s < kSplit; ++s) {
    const float wgt = __expf(m[s] - M);
    L += wgt * li[s];
    accv += wgt * Op[((size_t)s * kN + qrow) * kD + d];
  }
  out[(size_t)qrow * kD + d] = accv / L;
}

// ---------------------------------------------------------------------------
extern "C" void kernel_launch(void* const* d_in, const int* in_sizes, int n_in,
                              void* d_out, int out_size, void* d_ws, size_t ws_size,
                              hipStream_t stream)
{
  const float* q  = (const float*)d_in[0];
  const float* k  = (const float*)d_in[1];
  const float* v  = (const float*)d_in[2];
  const float* Wq = (const float*)d_in[3];
  const float* bq = (const float*)d_in[4];
  const float* Wk = (const float*)d_in[5];
  const float* bk = (const float*)d_in[6];
  const float* Wv = (const float*)d_in[7];
  const float* bv = (const float*)d_in[8];
  // d_in[9] = seq_len (unused: full-row softmax over all N tokens)

  char* ws = (char*)d_ws;
  short*  Qs = (short*)(ws);
  short*  Ks = (short*)(ws + ((size_t)4 << 20));
  short*  Vt = (short*)(ws + ((size_t)8 << 20));
  float*  Op = (float*)(ws + ((size_t)12 << 20));
  float2* Ml = (float2*)(ws + ((size_t)44 << 20));

  proj_kernel<<<dim3(kN / 64, kD / 64, 3), 256, 0, stream>>>(
      q, k, v, Wq, bq, Wk, bk, Wv, bv, Qs, Ks, Vt);
  flash_kernel<<<dim3(64, kSplit), 256, 0, stream>>>(Qs, Ks, Vt, Op, Ml);
  merge_kernel<<<dim3(kN), 256, 0, stream>>>(Op, Ml, (float*)d_out);
}